// Round 3
// baseline (187.388 us; speedup 1.0000x reference)
//
#include <hip/hip_runtime.h>
#include <stdint.h>

typedef __bf16 bf16x8 __attribute__((ext_vector_type(8)));
typedef float f32x4 __attribute__((ext_vector_type(4)));

#define N_ROWS 4096
#define KD 128
#define BM 64
#define BN 64
#define LDA 136   // LDS row stride in bf16: 128 + 8 pad (272 B)
#define NCHUNK 16
#define CHUNK 256 // 4096 / NCHUNK
#define NBLOCKS (64 * NCHUNK)

__device__ __forceinline__ unsigned short f32_to_bf16_rne(float f) {
    union { float f; uint32_t u; } v; v.f = f;
    uint32_t u = v.u;
    return (unsigned short)((u + 0x7FFFu + ((u >> 16) & 1u)) >> 16);
}

// One wave per row: L2-normalize, round to bf16 (RNE), pack 2 elems/lane.
// Block 0 also zeroes the gram kernel's completion ticket (kernel-boundary
// ordering guarantees visibility to gram's atomics).
__global__ __launch_bounds__(256) void normalize_kernel(const float* __restrict__ E,
                                                        unsigned short* __restrict__ out,
                                                        unsigned int* __restrict__ ticket) {
    if (blockIdx.x == 0 && threadIdx.x == 0) *ticket = 0u;
    const int wave = threadIdx.x >> 6;
    const int lane = threadIdx.x & 63;
    const int row = blockIdx.x * 4 + wave;
    const float2 v = *(const float2*)&E[row * KD + lane * 2];
    float s = v.x * v.x + v.y * v.y;
#pragma unroll
    for (int m = 1; m < 64; m <<= 1) s += __shfl_xor(s, m, 64);
    float inv = 0.0f;
    if (s > 0.0f) {
        inv = rsqrtf(s);
        inv = inv * (1.5f - 0.5f * s * inv * inv);  // Newton step: ~1e-7 rel err
    }
    const unsigned short a = f32_to_bf16_rne(v.x * inv);
    const unsigned short b = f32_to_bf16_rne(v.y * inv);
    ((uint32_t*)out)[row * (KD / 2) + lane] = ((uint32_t)b << 16) | a;
}

// Block = 64-row I-tile x 256-col J-chunk (1024 blocks = 4/CU). MFMA 16x16x32
// bf16 Gram tiles, fused hardest-pos/neg epilogue. Last-arriving block (device
// ticket) reduces all per-(row,chunk) partials to the scalar loss inline.
__global__ __launch_bounds__(256) void gram_kernel(const unsigned short* __restrict__ Ebits,
                                                   const int* __restrict__ labels,
                                                   float2* __restrict__ partials,
                                                   unsigned int* __restrict__ ticket,
                                                   float* __restrict__ out) {
    __shared__ unsigned short As[BM * LDA];
    __shared__ unsigned short Bs[BN * LDA];
    __shared__ int ljs[CHUNK];
    __shared__ unsigned int s_old;
    __shared__ float ssum[4];
    __shared__ int scnt[4];

    const int tid = threadIdx.x;
    const int itile = blockIdx.x & 63;
    const int chunk = blockIdx.x >> 6;
    const int ibase = itile * BM;
    const int cbase = chunk * CHUNK;

    // Stage A-tile (64 rows x 128 bf16 = 1024 uint4, coalesced) + chunk labels.
    {
        const uint4* src = (const uint4*)(Ebits + (size_t)ibase * KD);
#pragma unroll
        for (int it = 0; it < 4; ++it) {
            const int li = tid + it * 256;
            const int r = li >> 4, c = li & 15;
            *(uint4*)&As[r * LDA + c * 8] = src[li];
        }
        ljs[tid] = labels[cbase + tid];
    }
    __syncthreads();

    const int wave = tid >> 6, lane = tid & 63;
    const int quad = lane >> 4, l15 = lane & 15;

    // A fragments: A[m=lane&15][k=quad*8+j], held in regs for the whole chunk.
    bf16x8 afrag[4];
    const unsigned short* arow = &As[(wave * 16 + l15) * LDA + quad * 8];
#pragma unroll
    for (int s = 0; s < 4; ++s) afrag[s] = *(const bf16x8*)(arow + s * 32);

    int li_lab[4];
#pragma unroll
    for (int r = 0; r < 4; ++r) li_lab[r] = labels[ibase + wave * 16 + quad * 4 + r];

    float minpos[4] = {2.0f, 2.0f, 2.0f, 2.0f};    // dots in [-1,1]; 2.0 = "no positive"
    float maxneg[4] = {-2.0f, -2.0f, -2.0f, -2.0f};

    for (int jt = 0; jt < CHUNK / BN; ++jt) {
        const int jbase = cbase + jt * BN;
        __syncthreads();  // prev iter's Bs reads done
        {
            const uint4* src = (const uint4*)(Ebits + (size_t)jbase * KD);
#pragma unroll
            for (int it = 0; it < 4; ++it) {
                const int li = tid + it * 256;
                const int r = li >> 4, c = li & 15;
                *(uint4*)&Bs[r * LDA + c * 8] = src[li];
            }
        }
        __syncthreads();

#pragma unroll
        for (int t = 0; t < 4; ++t) {
            const unsigned short* brow = &Bs[(t * 16 + l15) * LDA + quad * 8];
            f32x4 acc = {0.f, 0.f, 0.f, 0.f};
#pragma unroll
            for (int s = 0; s < 4; ++s) {
                const bf16x8 bfrag = *(const bf16x8*)(brow + s * 32);
                acc = __builtin_amdgcn_mfma_f32_16x16x32_bf16(afrag[s], bfrag, acc, 0, 0, 0);
            }
            // C/D layout: col = lane&15 (j), row = quad*4 + reg (i)  [m89/m91]
            const int jg = jbase + t * 16 + l15;
            const int lj = ljs[jt * BN + t * 16 + l15];
#pragma unroll
            for (int r = 0; r < 4; ++r) {
                const int ig = ibase + wave * 16 + quad * 4 + r;
                const float d = acc[r];
                const bool same = (lj == li_lab[r]);
                const float dp = (same && (ig != jg)) ? d : 2.0f;
                const float dn = same ? -2.0f : d;
                minpos[r] = fminf(minpos[r], dp);
                maxneg[r] = fmaxf(maxneg[r], dn);
            }
        }
    }

    // Reduce across the 16 lanes of each quad (cols); rows live in (quad,reg).
#pragma unroll
    for (int m = 1; m < 16; m <<= 1) {
#pragma unroll
        for (int r = 0; r < 4; ++r) {
            minpos[r] = fminf(minpos[r], __shfl_xor(minpos[r], m, 64));
            maxneg[r] = fmaxf(maxneg[r], __shfl_xor(maxneg[r], m, 64));
        }
    }
    if (l15 == 0) {
#pragma unroll
        for (int r = 0; r < 4; ++r) {
            const int row = ibase + wave * 16 + quad * 4 + r;
            partials[row * NCHUNK + chunk] = make_float2(minpos[r], maxneg[r]);
        }
    }

    // ---- last-block finalize (device-scope release/acquire chain) ----
    __threadfence();                    // release partials (agent scope)
    __syncthreads();                    // all waves' stores issued before ticket
    if (tid == 0) s_old = atomicAdd(ticket, 1u);
    __syncthreads();
    if (s_old == (unsigned)(NBLOCKS - 1)) {
        __threadfence();                // acquire all other blocks' partials
        float sum = 0.f;
        int cnt = 0;
        for (int row = tid; row < N_ROWS; row += 256) {
            float mp = 2.f, mn = -2.f;
            const float4* p4 = (const float4*)&partials[row * NCHUNK];
#pragma unroll
            for (int c = 0; c < NCHUNK / 2; ++c) {
                const float4 v = p4[c];        // {min0,max0,min1,max1}
                mp = fminf(mp, fminf(v.x, v.z));
                mn = fmaxf(mn, fmaxf(v.y, v.w));
            }
            if (mp < 1.5f && mn > -1.5f) {     // valid: >=1 positive and >=1 negative
                sum += fmaxf(0.f, mn - mp + 0.3f);
                cnt += 1;
            }
        }
#pragma unroll
        for (int m = 1; m < 64; m <<= 1) {
            sum += __shfl_xor(sum, m, 64);
            cnt += __shfl_xor(cnt, m, 64);
        }
        if ((tid & 63) == 0) { ssum[tid >> 6] = sum; scnt[tid >> 6] = cnt; }
        __syncthreads();
        if (tid == 0) {
            const float S = ssum[0] + ssum[1] + ssum[2] + ssum[3];
            const int C = scnt[0] + scnt[1] + scnt[2] + scnt[3];
            out[0] = S / (float)(C > 0 ? C : 1);
        }
    }
}

extern "C" void kernel_launch(void* const* d_in, const int* in_sizes, int n_in,
                              void* d_out, int out_size, void* d_ws, size_t ws_size,
                              hipStream_t stream) {
    const float* E = (const float*)d_in[0];
    const int* labels = (const int*)d_in[1];

    unsigned short* ebits = (unsigned short*)d_ws;                          // 1 MiB
    float2* partials = (float2*)((char*)d_ws + (size_t)N_ROWS * KD * 2);    // 512 KiB
    unsigned int* ticket = (unsigned int*)(partials + N_ROWS * NCHUNK);     // 4 B
    float* out = (float*)d_out;

    normalize_kernel<<<N_ROWS / 4, 256, 0, stream>>>(E, ebits, ticket);
    gram_kernel<<<NBLOCKS, 256, 0, stream>>>(ebits, labels, partials, ticket, out);
}

// Round 4
// 87.056 us; speedup vs baseline: 2.1525x; 2.1525x over previous
//
#include <hip/hip_runtime.h>
#include <stdint.h>

typedef __bf16 bf16x8 __attribute__((ext_vector_type(8)));
typedef float f32x4 __attribute__((ext_vector_type(4)));

#define N_ROWS 4096
#define KD 128
#define BM 64
#define BN 64
#define NCHUNK 16
#define CHUNK 256 // 4096 / NCHUNK
#define NBLOCKS (64 * NCHUNK)

// Order-preserving float<->uint32 map: umin/umax on keys == fmin/fmax on floats.
__device__ __forceinline__ unsigned f2key(float f) {
    unsigned b = __float_as_uint(f);
    return (b & 0x80000000u) ? ~b : (b | 0x80000000u);
}
__device__ __forceinline__ float key2f(unsigned k) {
    unsigned b = (k & 0x80000000u) ? (k ^ 0x80000000u) : ~k;
    return __uint_as_float(b);
}

__device__ __forceinline__ unsigned short f32_to_bf16_rne(float f) {
    union { float f; uint32_t u; } v; v.f = f;
    uint32_t u = v.u;
    return (unsigned short)((u + 0x7FFFu + ((u >> 16) & 1u)) >> 16);
}

// One wave per row: L2-normalize, bf16 (RNE), pack 2/lane. Also inits the
// per-row min/max key slots and the ticket (visible to gram via the implicit
// end-of-kernel L2 writeback on the stream).
__global__ __launch_bounds__(256) void normalize_kernel(const float* __restrict__ E,
                                                        unsigned short* __restrict__ out,
                                                        unsigned* __restrict__ minkey,
                                                        unsigned* __restrict__ maxkey,
                                                        unsigned* __restrict__ ticket) {
    const int wave = threadIdx.x >> 6;
    const int lane = threadIdx.x & 63;
    const int row = blockIdx.x * 4 + wave;
    if (lane == 0) {
        minkey[row] = f2key(2.0f);    // "no positive" sentinel
        maxkey[row] = f2key(-2.0f);   // "no negative" sentinel
    }
    if (blockIdx.x == 0 && threadIdx.x == 0) *ticket = 0u;
    const float2 v = *(const float2*)&E[row * KD + lane * 2];
    float s = v.x * v.x + v.y * v.y;
#pragma unroll
    for (int m = 1; m < 64; m <<= 1) s += __shfl_xor(s, m, 64);
    float inv = 0.0f;
    if (s > 0.0f) {
        inv = rsqrtf(s);
        inv = inv * (1.5f - 0.5f * s * inv * inv);  // Newton step: ~1e-7 rel err
    }
    const unsigned short a = f32_to_bf16_rne(v.x * inv);
    const unsigned short b = f32_to_bf16_rne(v.y * inv);
    ((uint32_t*)out)[row * (KD / 2) + lane] = ((uint32_t)b << 16) | a;
}

// Block = 64-row I-tile x 256-col J-chunk (1024 blocks, 4/CU). Slab LDS layout:
// 16 slabs x 1024 B; slab sigma=(t*4+s) holds rows t*16+(lane&15), k-range
// s*32+(lane>>4)*8..+7 at byte lane*16 -> ds_read_b128 and staging writes are
// lane-contiguous (0 bank conflicts). Epilogue: relaxed device-scope
// atomicMin/Max on per-row keys; ticketed last block reduces 4096 rows inline.
__global__ __launch_bounds__(256) void gram_kernel(const unsigned short* __restrict__ Ebits,
                                                   const int* __restrict__ labels,
                                                   unsigned* __restrict__ minkey,
                                                   unsigned* __restrict__ maxkey,
                                                   unsigned* __restrict__ ticket,
                                                   float* __restrict__ out) {
    __shared__ uint4 As4[BM * KD / 8];   // 16 KB
    __shared__ uint4 Bs4[BN * KD / 8];   // 16 KB
    __shared__ int ljs[CHUNK];
    __shared__ unsigned s_old;
    __shared__ float ssum[4];
    __shared__ int scnt[4];

    const int tid = threadIdx.x;
    const int itile = blockIdx.x & 63;
    const int chunk = blockIdx.x >> 6;
    const int ibase = itile * BM;
    const int cbase = chunk * CHUNK;

    // Stage A-tile into slab order: LDS uint4 index L -> global uint4
    // g = (t*16+l)*16 + s*4 + q  with t=L>>8, s=(L>>6)&3, q=(L>>4)&3, l=L&15.
    {
        const uint4* src = (const uint4*)(Ebits + (size_t)ibase * KD);
#pragma unroll
        for (int it = 0; it < 4; ++it) {
            const int L = it * 256 + tid;
            const int t = L >> 8, s = (L >> 6) & 3, q = (L >> 4) & 3, l = L & 15;
            As4[L] = src[(t * 16 + l) * 16 + s * 4 + q];
        }
        ljs[tid] = labels[cbase + tid];
    }
    __syncthreads();

    const int wave = tid >> 6, lane = tid & 63;
    const int quad = lane >> 4, l15 = lane & 15;

    // A fragments: lane-contiguous b128 reads, held for the whole chunk.
    bf16x8 afrag[4];
#pragma unroll
    for (int s = 0; s < 4; ++s) afrag[s] = *(const bf16x8*)&As4[(wave * 4 + s) * 64 + lane];

    int li_lab[4];
#pragma unroll
    for (int r = 0; r < 4; ++r) li_lab[r] = labels[ibase + wave * 16 + quad * 4 + r];

    float minpos[4] = {2.0f, 2.0f, 2.0f, 2.0f};
    float maxneg[4] = {-2.0f, -2.0f, -2.0f, -2.0f};

    for (int jt = 0; jt < CHUNK / BN; ++jt) {
        const int jbase = cbase + jt * BN;
        __syncthreads();  // prev iter's Bs reads done
        {
            const uint4* src = (const uint4*)(Ebits + (size_t)jbase * KD);
#pragma unroll
            for (int it = 0; it < 4; ++it) {
                const int L = it * 256 + tid;
                const int t = L >> 8, s = (L >> 6) & 3, q = (L >> 4) & 3, l = L & 15;
                Bs4[L] = src[(t * 16 + l) * 16 + s * 4 + q];
            }
        }
        __syncthreads();

#pragma unroll
        for (int t = 0; t < 4; ++t) {
            f32x4 acc = {0.f, 0.f, 0.f, 0.f};
#pragma unroll
            for (int s = 0; s < 4; ++s) {
                const bf16x8 bfrag = *(const bf16x8*)&Bs4[(t * 4 + s) * 64 + lane];
                acc = __builtin_amdgcn_mfma_f32_16x16x32_bf16(afrag[s], bfrag, acc, 0, 0, 0);
            }
            // C/D layout: col = lane&15 (j), row = quad*4 + reg (i)  [m89/m91]
            const int jg = jbase + t * 16 + l15;
            const int lj = ljs[jt * BN + t * 16 + l15];
#pragma unroll
            for (int r = 0; r < 4; ++r) {
                const int ig = ibase + wave * 16 + quad * 4 + r;
                const float d = acc[r];
                const bool same = (lj == li_lab[r]);
                const float dp = (same && (ig != jg)) ? d : 2.0f;
                const float dn = same ? -2.0f : d;
                minpos[r] = fminf(minpos[r], dp);
                maxneg[r] = fmaxf(maxneg[r], dn);
            }
        }
    }

    // Reduce across the 16 col-lanes of each quad; rows live in (quad,reg).
#pragma unroll
    for (int m = 1; m < 16; m <<= 1) {
#pragma unroll
        for (int r = 0; r < 4; ++r) {
            minpos[r] = fminf(minpos[r], __shfl_xor(minpos[r], m, 64));
            maxneg[r] = fmaxf(maxneg[r], __shfl_xor(maxneg[r], m, 64));
        }
    }
    if (l15 == 0) {
#pragma unroll
        for (int r = 0; r < 4; ++r) {
            const int row = ibase + wave * 16 + quad * 4 + r;
            atomicMin(&minkey[row], f2key(minpos[r]));   // device-scope, relaxed: no cache ops
            atomicMax(&maxkey[row], f2key(maxneg[r]));
        }
    }

    // __syncthreads drains vmcnt(0) first -> all atomics performed at the
    // coherence point before the ticket increment. No fences (no L2 writeback).
    __syncthreads();
    if (tid == 0) s_old = atomicAdd(ticket, 1u);
    __syncthreads();
    if (s_old == (unsigned)(NBLOCKS - 1)) {
        float sum = 0.f;
        int cnt = 0;
        for (int row = tid; row < N_ROWS; row += 256) {
            // Agent-scope atomic loads: bypass (possibly stale) L1/L2.
            const unsigned mpk = __hip_atomic_load(&minkey[row], __ATOMIC_RELAXED,
                                                   __HIP_MEMORY_SCOPE_AGENT);
            const unsigned mnk = __hip_atomic_load(&maxkey[row], __ATOMIC_RELAXED,
                                                   __HIP_MEMORY_SCOPE_AGENT);
            const float mp = key2f(mpk);
            const float mn = key2f(mnk);
            if (mp < 1.5f && mn > -1.5f) {   // valid: >=1 positive and >=1 negative
                sum += fmaxf(0.f, mn - mp + 0.3f);
                cnt += 1;
            }
        }
#pragma unroll
        for (int m = 1; m < 64; m <<= 1) {
            sum += __shfl_xor(sum, m, 64);
            cnt += __shfl_xor(cnt, m, 64);
        }
        if ((tid & 63) == 0) { ssum[tid >> 6] = sum; scnt[tid >> 6] = cnt; }
        __syncthreads();
        if (tid == 0) {
            const float S = ssum[0] + ssum[1] + ssum[2] + ssum[3];
            const int C = scnt[0] + scnt[1] + scnt[2] + scnt[3];
            out[0] = S / (float)(C > 0 ? C : 1);
        }
    }
}

extern "C" void kernel_launch(void* const* d_in, const int* in_sizes, int n_in,
                              void* d_out, int out_size, void* d_ws, size_t ws_size,
                              hipStream_t stream) {
    const float* E = (const float*)d_in[0];
    const int* labels = (const int*)d_in[1];

    unsigned short* ebits = (unsigned short*)d_ws;                          // 1 MiB
    unsigned* minkey = (unsigned*)((char*)d_ws + (size_t)N_ROWS * KD * 2);  // 16 KiB
    unsigned* maxkey = minkey + N_ROWS;                                     // 16 KiB
    unsigned* ticket = maxkey + N_ROWS;                                     // 4 B
    float* out = (float*)d_out;

    normalize_kernel<<<N_ROWS / 4, 256, 0, stream>>>(E, ebits, minkey, maxkey, ticket);
    gram_kernel<<<NBLOCKS, 256, 0, stream>>>(ebits, labels, minkey, maxkey, ticket, out);
}